// Round 3
// baseline (262.092 us; speedup 1.0000x reference)
//
#include <hip/hip_runtime.h>

#define B_ 8
#define T_ 4000
#define D_ 512
#define L_ 8922
#define KSPLIT 8
#define KSTEPS_TOT 125   // T_/32
#define KCH 16           // K-steps per split chunk (last chunk = 13)

typedef __attribute__((ext_vector_type(8))) short short8;     // 8 bf16 (MFMA A/B frag)
typedef __attribute__((ext_vector_type(4))) float float4v;    // 4 f32 (MFMA C/D frag)
typedef __attribute__((ext_vector_type(4))) unsigned short us4;

__device__ inline unsigned short f2bf(float f) {
    unsigned u = __builtin_bit_cast(unsigned, f);
    return (unsigned short)((u + 0x7FFFu + ((u >> 16) & 1u)) >> 16);
}
__device__ inline float bf2f(unsigned short h) {
    unsigned u = ((unsigned)h) << 16;
    return __builtin_bit_cast(float, u);
}

// async global->LDS, 16B per lane; LDS dest = wave-uniform base + lane*16 (linear).
#define GLL(gp, lp)                                                            \
    __builtin_amdgcn_global_load_lds(                                          \
        (const __attribute__((address_space(1))) unsigned int*)(gp),           \
        (__attribute__((address_space(3))) unsigned int*)(lp), 16, 0, 0)

// Swizzled LDS offset (ushort units) of (row 0..127, 16B-chunk lg 0..3) in an
// 8KB [128 x 32 bf16] subtile. Row-pairs share a 128B line; chunk XOR'd with
// (pair&3) -> a wave's 64-lane b128 frag read = 64 distinct 16B slots, 0 conflicts
// (verified round 2: SQ_LDS_BANK_CONFLICT == 0). GLL dest stays linear; the
// GLOBAL source is pre-swizzled to match (both-sides-or-neither).
__device__ inline int swz(int row, int lg) {
    return ((row >> 1) << 6) + ((row & 1) << 5) + ((lg ^ ((row >> 1) & 3)) << 3);
}

// ---------------------------------------------------------------------------
// Kernel 1: uh = bf16(U_w), vh = bf16(final_w * proj_w)   [L, D]
// ---------------------------------------------------------------------------
__global__ __launch_bounds__(256) void cast_uv(const float* __restrict__ Uw,
                                               const float* __restrict__ Fw,
                                               const float* __restrict__ Pw,
                                               unsigned short* __restrict__ uh,
                                               unsigned short* __restrict__ vh) {
    const int total4 = (L_ * D_) / 4;
    int i = blockIdx.x * 256 + threadIdx.x;
    if (i >= total4) return;
    const int base = i * 4;
    const int d = base & (D_ - 1);
    float4 u4 = *(const float4*)(Uw + base);
    float4 f4 = *(const float4*)(Fw + base);
    float4 p4 = *(const float4*)(Pw + d);
    us4 uo, vo;
    uo.x = f2bf(u4.x); uo.y = f2bf(u4.y); uo.z = f2bf(u4.z); uo.w = f2bf(u4.w);
    vo.x = f2bf(f4.x * p4.x); vo.y = f2bf(f4.y * p4.y);
    vo.z = f2bf(f4.z * p4.z); vo.w = f2bf(f4.w * p4.w);
    *(us4*)(uh + base) = uo;
    *(us4*)(vh + base) = vo;
}

// ---------------------------------------------------------------------------
// Kernel 2: xT[b][d][t] = bf16(x[b][t][d])  (LDS-tiled 32x32 transpose)
// ---------------------------------------------------------------------------
__global__ __launch_bounds__(256) void transpose_x(const float* __restrict__ x,
                                                   unsigned short* __restrict__ xT) {
    __shared__ float tile[32][33];
    const int b = blockIdx.z;
    const int t0 = blockIdx.x * 32;
    const int d0 = blockIdx.y * 32;
    const int tx = threadIdx.x & 31, ty = threadIdx.x >> 5;
#pragma unroll
    for (int k = 0; k < 4; k++)
        tile[ty + 8 * k][tx] = x[(size_t)(b * T_ + t0 + ty + 8 * k) * D_ + d0 + tx];
    __syncthreads();
#pragma unroll
    for (int k = 0; k < 4; k++)
        xT[(size_t)(b * D_ + d0 + ty + 8 * k) * T_ + t0 + tx] = f2bf(tile[tx][ty + 8 * k]);
}

// ---------------------------------------------------------------------------
// Kernel 3: split-K symmetric Gram partials: Sf[b] += x_b^T x_b (upper tiles)
// 128x128 tile / 4 waves, BK=32. 3-deep LDS ring + counted vmcnt(4): the
// newest stage's 4 loads stay in flight ACROSS the barrier (T3/T4 minimal
// form); one s_barrier per step. f32 atomicAdd epilogue.
// ---------------------------------------------------------------------------
__global__ __launch_bounds__(256) void gramk(const unsigned short* __restrict__ xT,
                                             float* __restrict__ Sf) {
    __shared__ __align__(16) unsigned short lA[3][4096];
    __shared__ __align__(16) unsigned short lB[3][4096];
    const int tid = threadIdx.x;
    const int bid = blockIdx.x;
    const int b = bid & 7;              // batch == bid%8 -> one batch per XCD
    const int r2 = bid >> 3;            // 0..79
    const int tile = r2 % 10;
    const int ks = r2 / 10;             // 0..7
    int ti, tj;
    if (tile < 4)      { ti = 0; tj = tile; }
    else if (tile < 7) { ti = 1; tj = tile - 3; }
    else if (tile < 9) { ti = 2; tj = tile - 5; }
    else               { ti = 3; tj = 3; }
    const int i0 = ti * 128, j0 = tj * 128;
    const int kbeg = ks * KCH;
    const int nst = min(KSTEPS_TOT, kbeg + KCH) - kbeg;   // 16 or 13

    const int l = tid & 63;
    const int wv = tid >> 6, wr = wv >> 1, wc = wv & 1;
    const int lr = l & 15, lg = l >> 4;

    const float4v z4 = {0.f, 0.f, 0.f, 0.f};
    float4v acc[4][4];
#pragma unroll
    for (int m = 0; m < 4; m++)
#pragma unroll
        for (int n = 0; n < 4; n++) acc[m][n] = z4;

    // staging: thread tid -> linear LDS slot tid*16B; pre-swizzled source:
    const int rl = ((tid >> 3) << 1) | ((tid >> 2) & 1);
    const int sc = ((tid & 3) ^ ((tid >> 3) & 3)) << 3;
    const size_t xb = (size_t)b * D_ * T_;
    const unsigned short* gA0 = xT + xb + (size_t)(i0 + rl) * T_ + kbeg * 32 + sc;
    const unsigned short* gA1 = xT + xb + (size_t)(i0 + 64 + rl) * T_ + kbeg * 32 + sc;
    const unsigned short* gB0 = xT + xb + (size_t)(j0 + rl) * T_ + kbeg * 32 + sc;
    const unsigned short* gB1 = xT + xb + (size_t)(j0 + 64 + rl) * T_ + kbeg * 32 + sc;

#define STAGE_G(bf_, st_)                                                      \
    {                                                                          \
        GLL(gA0 + (st_) * 32, &lA[bf_][tid * 8]);                              \
        GLL(gA1 + (st_) * 32, &lA[bf_][2048 + tid * 8]);                       \
        GLL(gB0 + (st_) * 32, &lB[bf_][tid * 8]);                              \
        GLL(gB1 + (st_) * 32, &lB[bf_][2048 + tid * 8]);                       \
    }

    STAGE_G(0, 0);
    STAGE_G(1, 1);                      // nst >= 13 always
    int cur = 0;
    for (int s = 0; s < nst; ++s) {
        if (s == nst - 1) asm volatile("s_waitcnt vmcnt(0)" ::: "memory");
        else              asm volatile("s_waitcnt vmcnt(4)" ::: "memory");
        __builtin_amdgcn_s_barrier();
        asm volatile("" ::: "memory");
        if (s + 2 < nst) {
            int nb = cur + 2; if (nb >= 3) nb -= 3;
            STAGE_G(nb, s + 2);
        }
        short8 bfr[4];
#pragma unroll
        for (int n = 0; n < 4; n++)
            bfr[n] = *(const short8*)&lB[cur][swz(wc * 64 + n * 16 + lr, lg)];
        __builtin_amdgcn_s_setprio(1);
#pragma unroll
        for (int m = 0; m < 4; m++) {
            short8 a = *(const short8*)&lA[cur][swz(wr * 64 + m * 16 + lr, lg)];
#pragma unroll
            for (int n = 0; n < 4; n++)
                acc[m][n] = __builtin_amdgcn_mfma_f32_16x16x32_bf16(a, bfr[n], acc[m][n], 0, 0, 0);
        }
        __builtin_amdgcn_s_setprio(0);
        cur = (cur == 2) ? 0 : cur + 1;
    }
#undef STAGE_G

    float* Sb = Sf + (size_t)b * D_ * D_;
#pragma unroll
    for (int m = 0; m < 4; m++)
#pragma unroll
        for (int n = 0; n < 4; n++)
#pragma unroll
            for (int r = 0; r < 4; r++) {
                int row = i0 + wr * 64 + m * 16 + lg * 4 + r;
                int col = j0 + wc * 64 + n * 16 + lr;
                atomicAdd(&Sb[(size_t)row * D_ + col], acc[m][n][r]);
            }
}

// ---------------------------------------------------------------------------
// Kernel 4: Sh = bf16(dense S) from upper-tile Sf, mirroring lower tiles.
// ---------------------------------------------------------------------------
__global__ __launch_bounds__(256) void castS(const float* __restrict__ Sf,
                                             unsigned short* __restrict__ Sh) {
    int idx = blockIdx.x * 256 + threadIdx.x;
    int e = idx & (D_ * D_ / 4 - 1);
    int b = idx >> 16;
    int row = e >> 7;
    int col = (e & 127) << 2;
    const float* Sb = Sf + (size_t)b * D_ * D_;
    float4 v;
    if ((row >> 7) <= (col >> 7)) {
        v = *(const float4*)(Sb + (size_t)row * D_ + col);
    } else {
        v.x = Sb[(size_t)(col + 0) * D_ + row];
        v.y = Sb[(size_t)(col + 1) * D_ + row];
        v.z = Sb[(size_t)(col + 2) * D_ + row];
        v.w = Sb[(size_t)(col + 3) * D_ + row];
    }
    us4 o;
    o.x = f2bf(v.x); o.y = f2bf(v.y); o.z = f2bf(v.z); o.w = f2bf(v.w);
    *(us4*)(Sh + (size_t)b * D_ * D_ + (size_t)row * D_ + col) = o;
}

// ---------------------------------------------------------------------------
// Kernel 5: out[b][l] = final_b[l]
// ---------------------------------------------------------------------------
__global__ __launch_bounds__(256) void init_out(const float* __restrict__ fb,
                                                float* __restrict__ out) {
    int lk = blockIdx.x * 256 + threadIdx.x;
    int b = blockIdx.y;
    if (lk < L_) out[(size_t)b * L_ + lk] = fb[lk];
}

// ---------------------------------------------------------------------------
// Kernel 6: logits[b,l] += sum_d (U @ S_b)[l,d] * vh[l,d]
// 256(l) x 256(d) tile, 8 waves (2x4), 512 threads, BK=32, K=512.
// 3-deep LDS ring + counted vmcnt(4), one s_barrier per step, setprio around
// MFMA. Bijective XCD chunking: wg (w&7) gets contiguous l-tile-major work.
// Fused v-dot epilogue + atomicAdd. B = S_b row-major (symmetry).
// ---------------------------------------------------------------------------
__global__ __launch_bounds__(512, 2) void stage2(const unsigned short* __restrict__ uh,
                                                 const unsigned short* __restrict__ vh,
                                                 const unsigned short* __restrict__ Sh,
                                                 float* __restrict__ out) {
    __shared__ __align__(16) unsigned short lA[3][8192];   // 48KB: 3 x [256x32]
    __shared__ __align__(16) unsigned short lB[3][8192];   // 48KB
    __shared__ float red[4][256];                          //  4KB
    const int tid = threadIdx.x;
    // XCD chunking: nwg=560=8*70; XCD c=(wg&7) processes works [70c,70c+70),
    // ordered l-tile-major -> each XCD touches ~4.4 l-tiles of uh + all Sh.
    const int w = (blockIdx.x & 7) * 70 + (blockIdx.x >> 3);
    const int lt = w >> 4;              // 0..34 (w/16)
    const int rem = w & 15;
    const int dt = rem >> 3;            // 0..1
    const int b = rem & 7;
    const int l0 = lt * 256, d0 = dt * 256;

    const int l = tid & 63;
    const int wv = tid >> 6;            // 0..7
    const int wr = wv >> 2, wc = wv & 3;
    const int lr = l & 15, lg = l >> 4;

    const float4v z4 = {0.f, 0.f, 0.f, 0.f};
    float4v acc[8][4];
#pragma unroll
    for (int m = 0; m < 8; m++)
#pragma unroll
        for (int n = 0; n < 4; n++) acc[m][n] = z4;

    // staging: 512 threads; rows 0..127 per GLL round, +4096 halfwords = rows 128..255
    const int rl = ((tid >> 3) << 1) | ((tid >> 2) & 1);   // 0..127
    const int sc = ((tid & 3) ^ ((tid >> 3) & 3)) << 3;
    const int rA0 = min(l0 + rl, L_ - 1);                  // clamp tail (discarded)
    const int rA1 = min(l0 + 128 + rl, L_ - 1);
    const unsigned short* gA0 = uh + (size_t)rA0 * D_ + sc;
    const unsigned short* gA1 = uh + (size_t)rA1 * D_ + sc;
    const size_t sb = (size_t)b * D_ * D_;
    const unsigned short* gB0 = Sh + sb + (size_t)(d0 + rl) * D_ + sc;
    const unsigned short* gB1 = Sh + sb + (size_t)(d0 + 128 + rl) * D_ + sc;

#define STAGE_S(bf_, st_)                                                      \
    {                                                                          \
        GLL(gA0 + (st_) * 32, &lA[bf_][tid * 8]);                              \
        GLL(gA1 + (st_) * 32, &lA[bf_][4096 + tid * 8]);                       \
        GLL(gB0 + (st_) * 32, &lB[bf_][tid * 8]);                              \
        GLL(gB1 + (st_) * 32, &lB[bf_][4096 + tid * 8]);                       \
    }

    STAGE_S(0, 0);
    STAGE_S(1, 1);
    int cur = 0;
    for (int s = 0; s < 16; ++s) {
        if (s == 15) asm volatile("s_waitcnt vmcnt(0)" ::: "memory");
        else         asm volatile("s_waitcnt vmcnt(4)" ::: "memory");
        __builtin_amdgcn_s_barrier();
        asm volatile("" ::: "memory");
        if (s + 2 < 16) {
            int nb = cur + 2; if (nb >= 3) nb -= 3;
            STAGE_S(nb, s + 2);
        }
        short8 bfr[4];
#pragma unroll
        for (int n = 0; n < 4; n++) {
            int rb = wc * 64 + n * 16 + lr;
            bfr[n] = *(const short8*)&lB[cur][(rb >> 7) * 4096 + swz(rb & 127, lg)];
        }
        __builtin_amdgcn_s_setprio(1);
#pragma unroll
        for (int m = 0; m < 8; m++) {
            int ra = wr * 128 + m * 16 + lr;
            short8 a = *(const short8*)&lA[cur][(ra >> 7) * 4096 + swz(ra & 127, lg)];
#pragma unroll
            for (int n = 0; n < 4; n++)
                acc[m][n] = __builtin_amdgcn_mfma_f32_16x16x32_bf16(a, bfr[n], acc[m][n], 0, 0, 0);
        }
        __builtin_amdgcn_s_setprio(0);
        cur = (cur == 2) ? 0 : cur + 1;
    }
#undef STAGE_S

    // epilogue: multiply by vh[l,d], reduce over this wave's 64 d-cols
    float part[8][4];
#pragma unroll
    for (int m = 0; m < 8; m++)
#pragma unroll
        for (int r = 0; r < 4; r++) part[m][r] = 0.f;
#pragma unroll
    for (int m = 0; m < 8; m++)
#pragma unroll
        for (int n = 0; n < 4; n++) {
            int dcol = d0 + wc * 64 + n * 16 + lr;
#pragma unroll
            for (int r = 0; r < 4; r++) {
                int lrow = l0 + wr * 128 + m * 16 + lg * 4 + r;
                float v = bf2f(vh[(size_t)min(lrow, L_ - 1) * D_ + dcol]);
                part[m][r] += acc[m][n][r] * v;
            }
        }
#pragma unroll
    for (int off = 1; off < 16; off <<= 1)
#pragma unroll
        for (int m = 0; m < 8; m++)
#pragma unroll
            for (int r = 0; r < 4; r++)
                part[m][r] += __shfl_xor(part[m][r], off, 64);
    if (lr == 0) {
#pragma unroll
        for (int m = 0; m < 8; m++)
#pragma unroll
            for (int r = 0; r < 4; r++)
                red[wc][wr * 128 + m * 16 + lg * 4 + r] = part[m][r];
    }
    __syncthreads();
    if (tid < 256) {
        int lrow = l0 + tid;
        if (lrow < L_)
            atomicAdd(&out[(size_t)b * L_ + lrow],
                      red[0][tid] + red[1][tid] + red[2][tid] + red[3][tid]);
    }
}

// ---------------------------------------------------------------------------
extern "C" void kernel_launch(void* const* d_in, const int* in_sizes, int n_in,
                              void* d_out, int out_size, void* d_ws, size_t ws_size,
                              hipStream_t stream) {
    const float* x  = (const float*)d_in[0];
    const float* Uw = (const float*)d_in[1];
    const float* Fw = (const float*)d_in[2];
    const float* fb = (const float*)d_in[3];
    const float* Pw = (const float*)d_in[4];
    float* out = (float*)d_out;

    char* ws = (char*)d_ws;
    unsigned short* xT = (unsigned short*)(ws);                 // 32,768,000 B
    unsigned short* uh = (unsigned short*)(ws + 32768000);      //  9,136,128 B
    unsigned short* vh = (unsigned short*)(ws + 41904128);      //  9,136,128 B
    unsigned short* Sh = (unsigned short*)(ws + 51040256);      //  4,194,304 B
    float*          Sf = (float*)(ws + 55234560);               //  8,388,608 B (total ~63.6 MB)

    hipMemsetAsync(Sf, 0, (size_t)B_ * D_ * D_ * 4, stream);
    hipLaunchKernelGGL(cast_uv, dim3((L_ * D_ / 4 + 255) / 256), dim3(256), 0, stream,
                       Uw, Fw, Pw, uh, vh);
    hipLaunchKernelGGL(transpose_x, dim3(T_ / 32, D_ / 32, B_), dim3(256), 0, stream, x, xT);
    hipLaunchKernelGGL(gramk, dim3(8 * 10 * KSPLIT), dim3(256), 0, stream, xT, Sf);
    hipLaunchKernelGGL(castS, dim3(B_ * D_ * D_ / 4 / 256), dim3(256), 0, stream, Sf, Sh);
    hipLaunchKernelGGL(init_out, dim3((L_ + 255) / 256, B_), dim3(256), 0, stream, fb, out);
    hipLaunchKernelGGL(stage2, dim3(560), dim3(512), 0, stream, uh, vh, Sh, out);
}

// Round 5
// 251.700 us; speedup vs baseline: 1.0413x; 1.0413x over previous
//
#include <hip/hip_runtime.h>

#define B_ 8
#define T_ 4000
#define D_ 512
#define L_ 8922
#define KSPLIT 8
#define KSTEPS_TOT 125   // T_/32
#define KCH 16           // K-steps per split chunk (last chunk = 13)

typedef __attribute__((ext_vector_type(8))) short short8;     // 8 bf16 (MFMA A/B frag)
typedef __attribute__((ext_vector_type(4))) float float4v;    // 4 f32 (MFMA C/D frag)
typedef __attribute__((ext_vector_type(4))) unsigned short us4;

__device__ inline unsigned short f2bf(float f) {
    unsigned u = __builtin_bit_cast(unsigned, f);
    return (unsigned short)((u + 0x7FFFu + ((u >> 16) & 1u)) >> 16);
}
__device__ inline float bf2f(unsigned short h) {
    unsigned u = ((unsigned)h) << 16;
    return __builtin_bit_cast(float, u);
}

// async global->LDS, 16B per lane; LDS dest = wave-uniform base + lane*16 (linear).
#define GLL(gp, lp)                                                            \
    __builtin_amdgcn_global_load_lds(                                          \
        (const __attribute__((address_space(1))) unsigned int*)(gp),           \
        (__attribute__((address_space(3))) unsigned int*)(lp), 16, 0, 0)

// Swizzled LDS offset (ushort units) of (row 0..127, 16B-chunk lg 0..3) in an
// 8KB [128 x 32 bf16] subtile. Verified: SQ_LDS_BANK_CONFLICT == 0 (r2/r3).
// GLL dest stays linear; GLOBAL source is pre-swizzled (both-sides-or-neither).
__device__ inline int swz(int row, int lg) {
    return ((row >> 1) << 6) + ((row & 1) << 5) + ((lg ^ ((row >> 1) & 3)) << 3);
}

// ---------------------------------------------------------------------------
// Kernel 1: uh = bf16(U_w), vh = bf16(final_w * proj_w)   [L, D]
// ---------------------------------------------------------------------------
__global__ __launch_bounds__(256) void cast_uv(const float* __restrict__ Uw,
                                               const float* __restrict__ Fw,
                                               const float* __restrict__ Pw,
                                               unsigned short* __restrict__ uh,
                                               unsigned short* __restrict__ vh) {
    const int total4 = (L_ * D_) / 4;
    int i = blockIdx.x * 256 + threadIdx.x;
    if (i >= total4) return;
    const int base = i * 4;
    const int d = base & (D_ - 1);
    float4 u4 = *(const float4*)(Uw + base);
    float4 f4 = *(const float4*)(Fw + base);
    float4 p4 = *(const float4*)(Pw + d);
    us4 uo, vo;
    uo.x = f2bf(u4.x); uo.y = f2bf(u4.y); uo.z = f2bf(u4.z); uo.w = f2bf(u4.w);
    vo.x = f2bf(f4.x * p4.x); vo.y = f2bf(f4.y * p4.y);
    vo.z = f2bf(f4.z * p4.z); vo.w = f2bf(f4.w * p4.w);
    *(us4*)(uh + base) = uo;
    *(us4*)(vh + base) = vo;
}

// ---------------------------------------------------------------------------
// Kernel 2: xT[b][d][t] = bf16(x[b][t][d]); 32x32 tile; vectorized ushort4
// writes (4 t-values packed per thread), ~2-way (free) LDS read pattern.
// ---------------------------------------------------------------------------
__global__ __launch_bounds__(256) void transpose_x(const float* __restrict__ x,
                                                   unsigned short* __restrict__ xT) {
    __shared__ float tile[32][33];
    const int b = blockIdx.z;
    const int t0 = blockIdx.x * 32;
    const int d0 = blockIdx.y * 32;
    const int tx = threadIdx.x & 31, ty = threadIdx.x >> 5;  // ty: 0..7
#pragma unroll
    for (int k = 0; k < 4; k++)
        tile[ty + 8 * k][tx] = x[(size_t)(b * T_ + t0 + ty + 8 * k) * D_ + d0 + tx];
    __syncthreads();
    // write: thread -> d-row (tid>>3), t-chunk of 4 ((tid&7)*4); 8B packed store
    const int dd = threadIdx.x >> 3;
    const int tc = (threadIdx.x & 7) * 4;
    us4 o;
    o.x = f2bf(tile[tc + 0][dd]);
    o.y = f2bf(tile[tc + 1][dd]);
    o.z = f2bf(tile[tc + 2][dd]);
    o.w = f2bf(tile[tc + 3][dd]);
    *(us4*)(xT + (size_t)(b * D_ + d0 + dd) * T_ + t0 + tc) = o;
}

// ---------------------------------------------------------------------------
// Kernel 3: split-K symmetric Gram partials (unchanged from round 3).
// ---------------------------------------------------------------------------
__global__ __launch_bounds__(256) void gramk(const unsigned short* __restrict__ xT,
                                             float* __restrict__ Sf) {
    __shared__ __align__(16) unsigned short lA[3][4096];
    __shared__ __align__(16) unsigned short lB[3][4096];
    const int tid = threadIdx.x;
    const int bid = blockIdx.x;
    const int b = bid & 7;
    const int r2 = bid >> 3;
    const int tile = r2 % 10;
    const int ks = r2 / 10;
    int ti, tj;
    if (tile < 4)      { ti = 0; tj = tile; }
    else if (tile < 7) { ti = 1; tj = tile - 3; }
    else if (tile < 9) { ti = 2; tj = tile - 5; }
    else               { ti = 3; tj = 3; }
    const int i0 = ti * 128, j0 = tj * 128;
    const int kbeg = ks * KCH;
    const int nst = min(KSTEPS_TOT, kbeg + KCH) - kbeg;

    const int l = tid & 63;
    const int wv = tid >> 6, wr = wv >> 1, wc = wv & 1;
    const int lr = l & 15, lg = l >> 4;

    const float4v z4 = {0.f, 0.f, 0.f, 0.f};
    float4v acc[4][4];
#pragma unroll
    for (int m = 0; m < 4; m++)
#pragma unroll
        for (int n = 0; n < 4; n++) acc[m][n] = z4;

    const int rl = ((tid >> 3) << 1) | ((tid >> 2) & 1);
    const int sc = ((tid & 3) ^ ((tid >> 3) & 3)) << 3;
    const size_t xb = (size_t)b * D_ * T_;
    const unsigned short* gA0 = xT + xb + (size_t)(i0 + rl) * T_ + kbeg * 32 + sc;
    const unsigned short* gA1 = xT + xb + (size_t)(i0 + 64 + rl) * T_ + kbeg * 32 + sc;
    const unsigned short* gB0 = xT + xb + (size_t)(j0 + rl) * T_ + kbeg * 32 + sc;
    const unsigned short* gB1 = xT + xb + (size_t)(j0 + 64 + rl) * T_ + kbeg * 32 + sc;

#define STAGE_G(bf_, st_)                                                      \
    {                                                                          \
        GLL(gA0 + (st_) * 32, &lA[bf_][tid * 8]);                              \
        GLL(gA1 + (st_) * 32, &lA[bf_][2048 + tid * 8]);                       \
        GLL(gB0 + (st_) * 32, &lB[bf_][tid * 8]);                              \
        GLL(gB1 + (st_) * 32, &lB[bf_][2048 + tid * 8]);                       \
    }

    STAGE_G(0, 0);
    STAGE_G(1, 1);
    int cur = 0;
    for (int s = 0; s < nst; ++s) {
        if (s == nst - 1) asm volatile("s_waitcnt vmcnt(0)" ::: "memory");
        else              asm volatile("s_waitcnt vmcnt(4)" ::: "memory");
        __builtin_amdgcn_s_barrier();
        asm volatile("" ::: "memory");
        if (s + 2 < nst) {
            int nb = cur + 2; if (nb >= 3) nb -= 3;
            STAGE_G(nb, s + 2);
        }
        short8 bfr[4];
#pragma unroll
        for (int n = 0; n < 4; n++)
            bfr[n] = *(const short8*)&lB[cur][swz(wc * 64 + n * 16 + lr, lg)];
        __builtin_amdgcn_s_setprio(1);
#pragma unroll
        for (int m = 0; m < 4; m++) {
            short8 a = *(const short8*)&lA[cur][swz(wr * 64 + m * 16 + lr, lg)];
#pragma unroll
            for (int n = 0; n < 4; n++)
                acc[m][n] = __builtin_amdgcn_mfma_f32_16x16x32_bf16(a, bfr[n], acc[m][n], 0, 0, 0);
        }
        __builtin_amdgcn_s_setprio(0);
        cur = (cur == 2) ? 0 : cur + 1;
    }
#undef STAGE_G

    float* Sb = Sf + (size_t)b * D_ * D_;
#pragma unroll
    for (int m = 0; m < 4; m++)
#pragma unroll
        for (int n = 0; n < 4; n++)
#pragma unroll
            for (int r = 0; r < 4; r++) {
                int row = i0 + wr * 64 + m * 16 + lg * 4 + r;
                int col = j0 + wc * 64 + n * 16 + lr;
                atomicAdd(&Sb[(size_t)row * D_ + col], acc[m][n][r]);
            }
}

// ---------------------------------------------------------------------------
// Kernel 4: Sh = bf16(dense S) from upper-tile Sf, mirroring lower tiles.
// ---------------------------------------------------------------------------
__global__ __launch_bounds__(256) void castS(const float* __restrict__ Sf,
                                             unsigned short* __restrict__ Sh) {
    int idx = blockIdx.x * 256 + threadIdx.x;
    int e = idx & (D_ * D_ / 4 - 1);
    int b = idx >> 16;
    int row = e >> 7;
    int col = (e & 127) << 2;
    const float* Sb = Sf + (size_t)b * D_ * D_;
    float4 v;
    if ((row >> 7) <= (col >> 7)) {
        v = *(const float4*)(Sb + (size_t)row * D_ + col);
    } else {
        v.x = Sb[(size_t)(col + 0) * D_ + row];
        v.y = Sb[(size_t)(col + 1) * D_ + row];
        v.z = Sb[(size_t)(col + 2) * D_ + row];
        v.w = Sb[(size_t)(col + 3) * D_ + row];
    }
    us4 o;
    o.x = f2bf(v.x); o.y = f2bf(v.y); o.z = f2bf(v.z); o.w = f2bf(v.w);
    *(us4*)(Sh + (size_t)b * D_ * D_ + (size_t)row * D_ + col) = o;
}

// ---------------------------------------------------------------------------
// Kernel 5: out[b][l] = final_b[l]
// ---------------------------------------------------------------------------
__global__ __launch_bounds__(256) void init_out(const float* __restrict__ fb,
                                                float* __restrict__ out) {
    int lk = blockIdx.x * 256 + threadIdx.x;
    int b = blockIdx.y;
    if (lk < L_) out[(size_t)b * L_ + lk] = fb[lk];
}

// ---------------------------------------------------------------------------
// Kernel 6: logits[b,l] += sum_d (U @ S_b)[l,d] * vh[l,d]
// 256x256 tile, 8 waves, BK=64, 8 K-tiles. m201-style 4-phase/K-tile schedule:
// phase = one 128x128 C-quadrant (16 MFMA/wave) + stage one 16KB half-tile.
// Counted vmcnt(2/4/6/4) per phase (cross-wave retirement rule:
// N(q) = loads(q-2)+loads(q-1)); each half staged 4 phases before first read.
// Quadrant order Q(0,0),Q(0,1),Q(1,1),Q(1,0) maximizes A/B frag reuse
// (24 ds_read_b128 per K-tile per wave = minimum).
// ---------------------------------------------------------------------------
__global__ __launch_bounds__(512) void stage2(const unsigned short* __restrict__ uh,
                                              const unsigned short* __restrict__ vh,
                                              const unsigned short* __restrict__ Sh,
                                              float* __restrict__ out) {
    __shared__ __align__(16) unsigned short lA[2][2][2][4096];  // [buf][half][kk][128x32]
    __shared__ __align__(16) unsigned short lB[2][2][2][4096];
    __shared__ float red[4][256];
    const int tid = threadIdx.x;
    // bijective XCD chunking: 560 = 8 * 70, l-tile-major within each chunk
    const int w = (blockIdx.x & 7) * 70 + (blockIdx.x >> 3);
    const int lt = w >> 4;
    const int rem = w & 15;
    const int dt = rem >> 3;
    const int b = rem & 7;
    const int l0 = lt * 256, d0 = dt * 256;

    const int l = tid & 63;
    const int wv = tid >> 6;
    const int wro = (wv >> 2) * 64;     // row offset within quadrant (0/64)
    const int wco = (wv & 3) * 32;      // col offset within quadrant (0..96)
    const int lr = l & 15, lg = l >> 4;

    const float4v z4 = {0.f, 0.f, 0.f, 0.f};
    float4v acc[4][4][2];               // [quad][m][n]
#pragma unroll
    for (int q = 0; q < 4; q++)
#pragma unroll
        for (int m = 0; m < 4; m++)
#pragma unroll
            for (int n = 0; n < 2; n++) acc[q][m][n] = z4;

    const int rl = ((tid >> 3) << 1) | ((tid >> 2) & 1);       // 0..127
    const int sc = ((tid & 3) ^ ((tid >> 3) & 3)) << 3;
    const unsigned short* gA0s = uh + (size_t)min(l0 + rl, L_ - 1) * D_ + sc;
    const unsigned short* gA1s = uh + (size_t)min(l0 + 128 + rl, L_ - 1) * D_ + sc;
    const size_t sb = (size_t)b * D_ * D_;
    const unsigned short* gB0s = Sh + sb + (size_t)(d0 + rl) * D_ + sc;
    const unsigned short* gB1s = Sh + sb + (size_t)(d0 + 128 + rl) * D_ + sc;

#define STG_A0(bf_, kt_) { GLL(gA0s + (kt_) * 64, &lA[bf_][0][0][tid * 8]);    \
                           GLL(gA0s + (kt_) * 64 + 32, &lA[bf_][0][1][tid * 8]); }
#define STG_A1(bf_, kt_) { GLL(gA1s + (kt_) * 64, &lA[bf_][1][0][tid * 8]);    \
                           GLL(gA1s + (kt_) * 64 + 32, &lA[bf_][1][1][tid * 8]); }
#define STG_B0(bf_, kt_) { GLL(gB0s + (kt_) * 64, &lB[bf_][0][0][tid * 8]);    \
                           GLL(gB0s + (kt_) * 64 + 32, &lB[bf_][0][1][tid * 8]); }
#define STG_B1(bf_, kt_) { GLL(gB1s + (kt_) * 64, &lB[bf_][1][0][tid * 8]);    \
                           GLL(gB1s + (kt_) * 64 + 32, &lB[bf_][1][1][tid * 8]); }

    // prologue: stage all 4 halves of kt=0; land A0,B0; sync
    STG_A0(0, 0); STG_B0(0, 0); STG_B1(0, 0); STG_A1(0, 0);
    asm volatile("s_waitcnt vmcnt(4)" ::: "memory");
    __builtin_amdgcn_s_barrier();
    asm volatile("" ::: "memory");

    short8 af[4][2], b0f[2][2], b1f[2][2];

#define MFMA_Q(q_, bq_)                                                        \
    __builtin_amdgcn_s_setprio(1);                                             \
    _Pragma("unroll")                                                          \
    for (int m = 0; m < 4; m++)                                                \
        _Pragma("unroll")                                                      \
        for (int n = 0; n < 2; n++) {                                          \
            acc[q_][m][n] = __builtin_amdgcn_mfma_f32_16x16x32_bf16(           \
                af[m][0], bq_[n][0], acc[q_][m][n], 0, 0, 0);                  \
            acc[q_][m][n] = __builtin_amdgcn_mfma_f32_16x16x32_bf16(           \
                af[m][1], bq_[n][1], acc[q_][m][n], 0, 0, 0);                  \
        }                                                                      \
    __builtin_amdgcn_s_setprio(0);

    for (int kt = 0; kt < 8; ++kt) {
        const int bf = kt & 1, nb = bf ^ 1;
        const bool st = (kt < 7);
        // ---- phase 1: Q(0,0) — read A-half0 + B-half0; stage A0,B0 of kt+1
        asm volatile("s_waitcnt vmcnt(2)" ::: "memory");
#pragma unroll
        for (int m = 0; m < 4; m++) {
            af[m][0] = *(const short8*)&lA[bf][0][0][swz(wro + m * 16 + lr, lg)];
            af[m][1] = *(const short8*)&lA[bf][0][1][swz(wro + m * 16 + lr, lg)];
        }
#pragma unroll
        for (int n = 0; n < 2; n++) {
            b0f[n][0] = *(const short8*)&lB[bf][0][0][swz(wco + n * 16 + lr, lg)];
            b0f[n][1] = *(const short8*)&lB[bf][0][1][swz(wco + n * 16 + lr, lg)];
        }
        if (st) { STG_A0(nb, kt + 1); STG_B0(nb, kt + 1); }
        __builtin_amdgcn_s_barrier();
        MFMA_Q(0, b0f);
        __builtin_amdgcn_s_barrier();
        // ---- phase 2: Q(0,1) — read B-half1; stage B1 of kt+1
        if (st) asm volatile("s_waitcnt vmcnt(4)" ::: "memory");
        else    asm volatile("s_waitcnt vmcnt(0)" ::: "memory");
#pragma unroll
        for (int n = 0; n < 2; n++) {
            b1f[n][0] = *(const short8*)&lB[bf][1][0][swz(wco + n * 16 + lr, lg)];
            b1f[n][1] = *(const short8*)&lB[bf][1][1][swz(wco + n * 16 + lr, lg)];
        }
        if (st) STG_B1(nb, kt + 1);
        __builtin_amdgcn_s_barrier();
        MFMA_Q(1, b1f);
        __builtin_amdgcn_s_barrier();
        // ---- phase 3: Q(1,1) — read A-half1 (overwrite af); stage A1 of kt+1
        if (st) asm volatile("s_waitcnt vmcnt(6)" ::: "memory");
        else    asm volatile("s_waitcnt vmcnt(0)" ::: "memory");
#pragma unroll
        for (int m = 0; m < 4; m++) {
            af[m][0] = *(const short8*)&lA[bf][1][0][swz(wro + m * 16 + lr, lg)];
            af[m][1] = *(const short8*)&lA[bf][1][1][swz(wro + m * 16 + lr, lg)];
        }
        if (st) STG_A1(nb, kt + 1);
        __builtin_amdgcn_s_barrier();
        MFMA_Q(2, b1f);
        __builtin_amdgcn_s_barrier();
        // ---- phase 4: Q(1,0) — pure compute (reuse af, b0f); retire A0,B0 of kt+1
        if (st) asm volatile("s_waitcnt vmcnt(4)" ::: "memory");
        __builtin_amdgcn_s_barrier();
        MFMA_Q(3, b0f);
        __builtin_amdgcn_s_barrier();
    }
#undef MFMA_Q
#undef STG_A0
#undef STG_A1
#undef STG_B0
#undef STG_B1

    // epilogue: multiply by vh[l,d], reduce over d.
    // quad q -> (mh, nh): 0:(0,0) 1:(0,1) 2:(1,1) 3:(1,0)
    const int qmh[4] = {0, 0, 1, 1};
    const int qnh[4] = {0, 1, 1, 0};
    float part[2][4][4];                // [mh][m][r]
#pragma unroll
    for (int h = 0; h < 2; h++)
#pragma unroll
        for (int m = 0; m < 4; m++)
#pragma unroll
            for (int r = 0; r < 4; r++) part[h][m][r] = 0.f;
#pragma unroll
    for (int q = 0; q < 4; q++) {
        const int mh = qmh[q], nh = qnh[q];
#pragma unroll
        for (int m = 0; m < 4; m++)
#pragma unroll
            for (int n = 0; n < 2; n++) {
                int dcol = d0 + nh * 128 + wco + n * 16 + lr;
#pragma unroll
                for (int r = 0; r < 4; r++) {
                    int lrow = l0 + mh * 128 + wro + m * 16 + lg * 4 + r;
                    float v = bf2f(vh[(size_t)min(lrow, L_ - 1) * D_ + dcol]);
                    part[mh][m][r] += acc[q][m][n][r] * v;
                }
            }
    }
#pragma unroll
    for (int off = 1; off < 16; off <<= 1)
#pragma unroll
        for (int h = 0; h < 2; h++)
#pragma unroll
            for (int m = 0; m < 4; m++)
#pragma unroll
                for (int r = 0; r < 4; r++)
                    part[h][m][r] += __shfl_xor(part[h][m][r], off, 64);
    if (lr == 0) {
#pragma unroll
        for (int h = 0; h < 2; h++)
#pragma unroll
            for (int m = 0; m < 4; m++)
#pragma unroll
                for (int r = 0; r < 4; r++)
                    red[wv & 3][h * 128 + wro + m * 16 + lg * 4 + r] = part[h][m][r];
    }
    __syncthreads();
    if (tid < 256) {
        int lrow = l0 + tid;
        if (lrow < L_)
            atomicAdd(&out[(size_t)b * L_ + lrow],
                      red[0][tid] + red[1][tid] + red[2][tid] + red[3][tid]);
    }
}

// ---------------------------------------------------------------------------
extern "C" void kernel_launch(void* const* d_in, const int* in_sizes, int n_in,
                              void* d_out, int out_size, void* d_ws, size_t ws_size,
                              hipStream_t stream) {
    const float* x  = (const float*)d_in[0];
    const float* Uw = (const float*)d_in[1];
    const float* Fw = (const float*)d_in[2];
    const float* fb = (const float*)d_in[3];
    const float* Pw = (const float*)d_in[4];
    float* out = (float*)d_out;

    char* ws = (char*)d_ws;
    unsigned short* xT = (unsigned short*)(ws);                 // 32,768,000 B
    unsigned short* uh = (unsigned short*)(ws + 32768000);      //  9,136,128 B
    unsigned short* vh = (unsigned short*)(ws + 41904128);      //  9,136,128 B
    unsigned short* Sh = (unsigned short*)(ws + 51040256);      //  4,194,304 B
    float*          Sf = (float*)(ws + 55234560);               //  8,388,608 B (total ~63.6 MB)

    hipMemsetAsync(Sf, 0, (size_t)B_ * D_ * D_ * 4, stream);
    hipLaunchKernelGGL(cast_uv, dim3((L_ * D_ / 4 + 255) / 256), dim3(256), 0, stream,
                       Uw, Fw, Pw, uh, vh);
    hipLaunchKernelGGL(transpose_x, dim3(T_ / 32, D_ / 32, B_), dim3(256), 0, stream, x, xT);
    hipLaunchKernelGGL(gramk, dim3(8 * 10 * KSPLIT), dim3(256), 0, stream, xT, Sf);
    hipLaunchKernelGGL(castS, dim3(B_ * D_ * D_ / 4 / 256), dim3(256), 0, stream, Sf, Sh);
    hipLaunchKernelGGL(init_out, dim3((L_ + 255) / 256, B_), dim3(256), 0, stream, fb, out);
    hipLaunchKernelGGL(stage2, dim3(560), dim3(512), 0, stream, uh, vh, Sh, out);
}

// Round 6
// 248.761 us; speedup vs baseline: 1.0536x; 1.0118x over previous
//
#include <hip/hip_runtime.h>

#define B_ 8
#define T_ 4000
#define D_ 512
#define L_ 8922
#define KSPLIT 8
#define KSTEPS_TOT 125   // T_/32
#define KCH 16           // K-steps per split chunk (last chunk = 13)

typedef __attribute__((ext_vector_type(8))) short short8;     // 8 bf16 (MFMA A/B frag)
typedef __attribute__((ext_vector_type(4))) float float4v;    // 4 f32 (MFMA C/D frag)
typedef __attribute__((ext_vector_type(4))) unsigned short us4;

__device__ inline unsigned short f2bf(float f) {
    unsigned u = __builtin_bit_cast(unsigned, f);
    return (unsigned short)((u + 0x7FFFu + ((u >> 16) & 1u)) >> 16);
}
__device__ inline float bf2f(unsigned short h) {
    unsigned u = ((unsigned)h) << 16;
    return __builtin_bit_cast(float, u);
}

// async global->LDS, 16B per lane; LDS dest = wave-uniform base + lane*16 (linear).
#define GLL(gp, lp)                                                            \
    __builtin_amdgcn_global_load_lds(                                          \
        (const __attribute__((address_space(1))) unsigned int*)(gp),           \
        (__attribute__((address_space(3))) unsigned int*)(lp), 16, 0, 0)

// Swizzled LDS offset (ushort units) of (row 0..127, 16B-chunk lg 0..3) in an
// 8KB [128 x 32 bf16] subtile. Verified: SQ_LDS_BANK_CONFLICT == 0 (r2/r3/r5).
// GLL dest stays linear; GLOBAL source is pre-swizzled (both-sides-or-neither).
__device__ inline int swz(int row, int lg) {
    return ((row >> 1) << 6) + ((row & 1) << 5) + ((lg ^ ((row >> 1) & 3)) << 3);
}

// ---------------------------------------------------------------------------
// Kernel 1: uh = bf16(U_w), vh = bf16(final_w * proj_w)   [L, D]
// ---------------------------------------------------------------------------
__global__ __launch_bounds__(256) void cast_uv(const float* __restrict__ Uw,
                                               const float* __restrict__ Fw,
                                               const float* __restrict__ Pw,
                                               unsigned short* __restrict__ uh,
                                               unsigned short* __restrict__ vh) {
    const int total4 = (L_ * D_) / 4;
    int i = blockIdx.x * 256 + threadIdx.x;
    if (i >= total4) return;
    const int base = i * 4;
    const int d = base & (D_ - 1);
    float4 u4 = *(const float4*)(Uw + base);
    float4 f4 = *(const float4*)(Fw + base);
    float4 p4 = *(const float4*)(Pw + d);
    us4 uo, vo;
    uo.x = f2bf(u4.x); uo.y = f2bf(u4.y); uo.z = f2bf(u4.z); uo.w = f2bf(u4.w);
    vo.x = f2bf(f4.x * p4.x); vo.y = f2bf(f4.y * p4.y);
    vo.z = f2bf(f4.z * p4.z); vo.w = f2bf(f4.w * p4.w);
    *(us4*)(uh + base) = uo;
    *(us4*)(vh + base) = vo;
}

// ---------------------------------------------------------------------------
// Kernel 2: xT[b][d][t] = bf16(x[b][t][d]); 32x32 tile.
// float4 global loads (128B / 8 lanes), LDS pad 41 (<=2-way, free), us4 stores.
// ---------------------------------------------------------------------------
__global__ __launch_bounds__(256) void transpose_x(const float* __restrict__ x,
                                                   unsigned short* __restrict__ xT) {
    __shared__ float tile[32][41];
    const int b = blockIdx.z;
    const int t0 = blockIdx.x * 32;
    const int d0 = blockIdx.y * 32;
    const int t = threadIdx.x >> 3, dc = (threadIdx.x & 7) * 4;
    float4 v = *(const float4*)(x + (size_t)(b * T_ + t0 + t) * D_ + d0 + dc);
    tile[t][dc] = v.x; tile[t][dc + 1] = v.y;
    tile[t][dc + 2] = v.z; tile[t][dc + 3] = v.w;
    __syncthreads();
    const int d = threadIdx.x >> 3, tc = (threadIdx.x & 7) * 4;
    us4 o;
    o.x = f2bf(tile[tc + 0][d]);
    o.y = f2bf(tile[tc + 1][d]);
    o.z = f2bf(tile[tc + 2][d]);
    o.w = f2bf(tile[tc + 3][d]);
    *(us4*)(xT + (size_t)(b * D_ + d0 + d) * T_ + t0 + tc) = o;
}

// ---------------------------------------------------------------------------
// Kernel 3: split-K symmetric Gram partials (proven structure, unchanged).
// ---------------------------------------------------------------------------
__global__ __launch_bounds__(256) void gramk(const unsigned short* __restrict__ xT,
                                             float* __restrict__ Sf) {
    __shared__ __align__(16) unsigned short lA[3][4096];
    __shared__ __align__(16) unsigned short lB[3][4096];
    const int tid = threadIdx.x;
    const int bid = blockIdx.x;
    const int b = bid & 7;
    const int r2 = bid >> 3;
    const int tile = r2 % 10;
    const int ks = r2 / 10;
    int ti, tj;
    if (tile < 4)      { ti = 0; tj = tile; }
    else if (tile < 7) { ti = 1; tj = tile - 3; }
    else if (tile < 9) { ti = 2; tj = tile - 5; }
    else               { ti = 3; tj = 3; }
    const int i0 = ti * 128, j0 = tj * 128;
    const int kbeg = ks * KCH;
    const int nst = min(KSTEPS_TOT, kbeg + KCH) - kbeg;

    const int l = tid & 63;
    const int wv = tid >> 6, wr = wv >> 1, wc = wv & 1;
    const int lr = l & 15, lg = l >> 4;

    const float4v z4 = {0.f, 0.f, 0.f, 0.f};
    float4v acc[4][4];
#pragma unroll
    for (int m = 0; m < 4; m++)
#pragma unroll
        for (int n = 0; n < 4; n++) acc[m][n] = z4;

    const int rl = ((tid >> 3) << 1) | ((tid >> 2) & 1);
    const int sc = ((tid & 3) ^ ((tid >> 3) & 3)) << 3;
    const size_t xb = (size_t)b * D_ * T_;
    const unsigned short* gA0 = xT + xb + (size_t)(i0 + rl) * T_ + kbeg * 32 + sc;
    const unsigned short* gA1 = xT + xb + (size_t)(i0 + 64 + rl) * T_ + kbeg * 32 + sc;
    const unsigned short* gB0 = xT + xb + (size_t)(j0 + rl) * T_ + kbeg * 32 + sc;
    const unsigned short* gB1 = xT + xb + (size_t)(j0 + 64 + rl) * T_ + kbeg * 32 + sc;

#define STAGE_G(bf_, st_)                                                      \
    {                                                                          \
        GLL(gA0 + (st_) * 32, &lA[bf_][tid * 8]);                              \
        GLL(gA1 + (st_) * 32, &lA[bf_][2048 + tid * 8]);                       \
        GLL(gB0 + (st_) * 32, &lB[bf_][tid * 8]);                              \
        GLL(gB1 + (st_) * 32, &lB[bf_][2048 + tid * 8]);                       \
    }

    STAGE_G(0, 0);
    STAGE_G(1, 1);
    int cur = 0;
    for (int s = 0; s < nst; ++s) {
        if (s == nst - 1) asm volatile("s_waitcnt vmcnt(0)" ::: "memory");
        else              asm volatile("s_waitcnt vmcnt(4)" ::: "memory");
        __builtin_amdgcn_s_barrier();
        asm volatile("" ::: "memory");
        if (s + 2 < nst) {
            int nb = cur + 2; if (nb >= 3) nb -= 3;
            STAGE_G(nb, s + 2);
        }
        short8 bfr[4];
#pragma unroll
        for (int n = 0; n < 4; n++)
            bfr[n] = *(const short8*)&lB[cur][swz(wc * 64 + n * 16 + lr, lg)];
        __builtin_amdgcn_s_setprio(1);
#pragma unroll
        for (int m = 0; m < 4; m++) {
            short8 a = *(const short8*)&lA[cur][swz(wr * 64 + m * 16 + lr, lg)];
#pragma unroll
            for (int n = 0; n < 4; n++)
                acc[m][n] = __builtin_amdgcn_mfma_f32_16x16x32_bf16(a, bfr[n], acc[m][n], 0, 0, 0);
        }
        __builtin_amdgcn_s_setprio(0);
        cur = (cur == 2) ? 0 : cur + 1;
    }
#undef STAGE_G

    float* Sb = Sf + (size_t)b * D_ * D_;
#pragma unroll
    for (int m = 0; m < 4; m++)
#pragma unroll
        for (int n = 0; n < 4; n++)
#pragma unroll
            for (int r = 0; r < 4; r++) {
                int row = i0 + wr * 64 + m * 16 + lg * 4 + r;
                int col = j0 + wc * 64 + n * 16 + lr;
                atomicAdd(&Sb[(size_t)row * D_ + col], acc[m][n][r]);
            }
}

// ---------------------------------------------------------------------------
// Kernel 4: Sh = bf16(dense S) from upper-tile Sf (mirror), PLUS fused
// out[b][l] = final_b[l] init (blocks >= 2048).
// ---------------------------------------------------------------------------
__global__ __launch_bounds__(256) void castS_init(const float* __restrict__ Sf,
                                                  unsigned short* __restrict__ Sh,
                                                  const float* __restrict__ fb,
                                                  float* __restrict__ out) {
    if (blockIdx.x >= 2048) {
        int k = (blockIdx.x - 2048) * 256 + threadIdx.x;
        if (k < B_ * L_) {
            int b = k / L_;
            out[k] = fb[k - b * L_];
        }
        return;
    }
    int idx = blockIdx.x * 256 + threadIdx.x;
    int e = idx & (D_ * D_ / 4 - 1);
    int b = idx >> 16;
    int row = e >> 7;
    int col = (e & 127) << 2;
    const float* Sb = Sf + (size_t)b * D_ * D_;
    float4 v;
    if ((row >> 7) <= (col >> 7)) {
        v = *(const float4*)(Sb + (size_t)row * D_ + col);
    } else {
        v.x = Sb[(size_t)(col + 0) * D_ + row];
        v.y = Sb[(size_t)(col + 1) * D_ + row];
        v.z = Sb[(size_t)(col + 2) * D_ + row];
        v.w = Sb[(size_t)(col + 3) * D_ + row];
    }
    us4 o;
    o.x = f2bf(v.x); o.y = f2bf(v.y); o.z = f2bf(v.z); o.w = f2bf(v.w);
    *(us4*)(Sh + (size_t)b * D_ * D_ + (size_t)row * D_ + col) = o;
}

// ---------------------------------------------------------------------------
// Kernel 5: logits[b,l] += sum_d (U @ S_b)[l,d] * vh[l,d]
// 128(l) x 128(d) tile, 4 waves (256 thr), K=512 (16 steps BK=32).
// 3-deep LDS ring + counted vmcnt(4) (gramk's proven loop), setprio,
// 49 KB LDS -> 3 blocks/CU resident, grid 2240 (no tail), XCD lt-major
// chunking (2240 = 8 x 280). Fused v-dot epilogue + atomicAdd (r2-proven).
// ---------------------------------------------------------------------------
__global__ __launch_bounds__(256) void stage2(const unsigned short* __restrict__ uh,
                                              const unsigned short* __restrict__ vh,
                                              const unsigned short* __restrict__ Sh,
                                              float* __restrict__ out) {
    __shared__ __align__(16) unsigned short lA[3][4096];
    __shared__ __align__(16) unsigned short lB[3][4096];
    __shared__ float red[2][128];
    const int tid = threadIdx.x;
    // XCD chunk: xcd = bid&7 gets 280 contiguous work items, lt-major
    // (per lt: 4 dt x 8 b = 32 items -> each XCD owns ~8.75 lt of uh rows).
    const int w = (blockIdx.x & 7) * 280 + (blockIdx.x >> 3);
    const int lt = w >> 5;
    const int rem = w & 31;
    const int dt = rem >> 3;
    const int b = rem & 7;
    const int l0 = lt * 128, d0 = dt * 128;
    const int l = tid & 63;
    const int wv = tid >> 6, wr = wv >> 1, wc = wv & 1;
    const int lr = l & 15, lg = l >> 4;

    const float4v z4 = {0.f, 0.f, 0.f, 0.f};
    float4v acc[4][4];
#pragma unroll
    for (int m = 0; m < 4; m++)
#pragma unroll
        for (int n = 0; n < 4; n++) acc[m][n] = z4;

    const int rl = ((tid >> 3) << 1) | ((tid >> 2) & 1);
    const int sc = ((tid & 3) ^ ((tid >> 3) & 3)) << 3;
    const int rA0 = min(l0 + rl, L_ - 1);          // clamp tail (discarded later)
    const int rA1 = min(l0 + 64 + rl, L_ - 1);
    const unsigned short* gA0 = uh + (size_t)rA0 * D_ + sc;
    const unsigned short* gA1 = uh + (size_t)rA1 * D_ + sc;
    const size_t sb = (size_t)b * D_ * D_;
    const unsigned short* gB0 = Sh + sb + (size_t)(d0 + rl) * D_ + sc;
    const unsigned short* gB1 = Sh + sb + (size_t)(d0 + 64 + rl) * D_ + sc;

#define STAGE_S(bf_, st_)                                                      \
    {                                                                          \
        GLL(gA0 + (st_) * 32, &lA[bf_][tid * 8]);                              \
        GLL(gA1 + (st_) * 32, &lA[bf_][2048 + tid * 8]);                       \
        GLL(gB0 + (st_) * 32, &lB[bf_][tid * 8]);                              \
        GLL(gB1 + (st_) * 32, &lB[bf_][2048 + tid * 8]);                       \
    }

    STAGE_S(0, 0);
    STAGE_S(1, 1);
    int cur = 0;
    for (int s = 0; s < 16; ++s) {
        if (s == 15) asm volatile("s_waitcnt vmcnt(0)" ::: "memory");
        else         asm volatile("s_waitcnt vmcnt(4)" ::: "memory");
        __builtin_amdgcn_s_barrier();
        asm volatile("" ::: "memory");
        if (s + 2 < 16) {
            int nb = cur + 2; if (nb >= 3) nb -= 3;
            STAGE_S(nb, s + 2);
        }
        short8 bfr[4];
#pragma unroll
        for (int n = 0; n < 4; n++)
            bfr[n] = *(const short8*)&lB[cur][swz(wc * 64 + n * 16 + lr, lg)];
        __builtin_amdgcn_s_setprio(1);
#pragma unroll
        for (int m = 0; m < 4; m++) {
            short8 a = *(const short8*)&lA[cur][swz(wr * 64 + m * 16 + lr, lg)];
#pragma unroll
            for (int n = 0; n < 4; n++)
                acc[m][n] = __builtin_amdgcn_mfma_f32_16x16x32_bf16(a, bfr[n], acc[m][n], 0, 0, 0);
        }
        __builtin_amdgcn_s_setprio(0);
        cur = (cur == 2) ? 0 : cur + 1;
    }
#undef STAGE_S

    // epilogue: multiply by vh[l,d], reduce over d (r2-proven mapping)
    float part[4][4];
#pragma unroll
    for (int m = 0; m < 4; m++)
#pragma unroll
        for (int r = 0; r < 4; r++) part[m][r] = 0.f;
#pragma unroll
    for (int m = 0; m < 4; m++)
#pragma unroll
        for (int n = 0; n < 4; n++) {
            int dcol = d0 + wc * 64 + n * 16 + lr;
#pragma unroll
            for (int r = 0; r < 4; r++) {
                int lrow = l0 + wr * 64 + m * 16 + lg * 4 + r;
                float v = bf2f(vh[(size_t)min(lrow, L_ - 1) * D_ + dcol]);
                part[m][r] += acc[m][n][r] * v;
            }
        }
#pragma unroll
    for (int off = 1; off < 16; off <<= 1)
#pragma unroll
        for (int m = 0; m < 4; m++)
#pragma unroll
            for (int r = 0; r < 4; r++)
                part[m][r] += __shfl_xor(part[m][r], off, 64);
    if (lr == 0) {
#pragma unroll
        for (int m = 0; m < 4; m++)
#pragma unroll
            for (int r = 0; r < 4; r++)
                red[wc][wr * 64 + m * 16 + lg * 4 + r] = part[m][r];
    }
    __syncthreads();
    if (tid < 128) {
        int lrow = l0 + tid;
        if (lrow < L_) atomicAdd(&out[(size_t)b * L_ + lrow], red[0][tid] + red[1][tid]);
    }
}

// ---------------------------------------------------------------------------
extern "C" void kernel_launch(void* const* d_in, const int* in_sizes, int n_in,
                              void* d_out, int out_size, void* d_ws, size_t ws_size,
                              hipStream_t stream) {
    const float* x  = (const float*)d_in[0];
    const float* Uw = (const float*)d_in[1];
    const float* Fw = (const float*)d_in[2];
    const float* fb = (const float*)d_in[3];
    const float* Pw = (const float*)d_in[4];
    float* out = (float*)d_out;

    char* ws = (char*)d_ws;
    unsigned short* xT = (unsigned short*)(ws);                 // 32,768,000 B
    unsigned short* uh = (unsigned short*)(ws + 32768000);      //  9,136,128 B
    unsigned short* vh = (unsigned short*)(ws + 41904128);      //  9,136,128 B
    unsigned short* Sh = (unsigned short*)(ws + 51040256);      //  4,194,304 B
    float*          Sf = (float*)(ws + 55234560);               //  8,388,608 B (total ~63.6 MB)

    hipMemsetAsync(Sf, 0, (size_t)B_ * D_ * D_ * 4, stream);
    hipLaunchKernelGGL(cast_uv, dim3((L_ * D_ / 4 + 255) / 256), dim3(256), 0, stream,
                       Uw, Fw, Pw, uh, vh);
    hipLaunchKernelGGL(transpose_x, dim3(T_ / 32, D_ / 32, B_), dim3(256), 0, stream, x, xT);
    hipLaunchKernelGGL(gramk, dim3(8 * 10 * KSPLIT), dim3(256), 0, stream, xT, Sf);
    hipLaunchKernelGGL(castS_init, dim3(2048 + (B_ * L_ + 255) / 256), dim3(256), 0, stream,
                       Sf, Sh, fb, out);
    hipLaunchKernelGGL(stage2, dim3(2240), dim3(256), 0, stream, uh, vh, Sh, out);
}

// Round 8
// 246.186 us; speedup vs baseline: 1.0646x; 1.0105x over previous
//
#include <hip/hip_runtime.h>

#define B_ 8
#define T_ 4000
#define D_ 512
#define L_ 8922
#define KSPLIT 4
#define KSTEPS_TOT 125   // T_/32
#define KCH 32           // K-steps per split chunk (last chunk = 29)

typedef __attribute__((ext_vector_type(8))) short short8;     // 8 bf16 (MFMA A/B frag)
typedef __attribute__((ext_vector_type(4))) float float4v;    // 4 f32 (MFMA C/D frag)
typedef __attribute__((ext_vector_type(4))) unsigned short us4;

__device__ inline unsigned short f2bf(float f) {
    unsigned u = __builtin_bit_cast(unsigned, f);
    return (unsigned short)((u + 0x7FFFu + ((u >> 16) & 1u)) >> 16);
}
__device__ inline float bf2f(unsigned short h) {
    unsigned u = ((unsigned)h) << 16;
    return __builtin_bit_cast(float, u);
}

// async global->LDS, 16B per lane; LDS dest = wave-uniform base + lane*16 (linear).
#define GLL(gp, lp)                                                            \
    __builtin_amdgcn_global_load_lds(                                          \
        (const __attribute__((address_space(1))) unsigned int*)(gp),           \
        (__attribute__((address_space(3))) unsigned int*)(lp), 16, 0, 0)

// Swizzled LDS offset (ushort units) of (row 0..127, 16B-chunk lg 0..3) in an
// 8KB [128 x 32 bf16] subtile. Verified: SQ_LDS_BANK_CONFLICT == 0 (r2/r3/r5/r6).
// GLL dest stays linear; GLOBAL source is pre-swizzled (both-sides-or-neither).
__device__ inline int swz(int row, int lg) {
    return ((row >> 1) << 6) + ((row & 1) << 5) + ((lg ^ ((row >> 1) & 3)) << 3);
}

// ---------------------------------------------------------------------------
// Kernel 1: uh = bf16(U_w), vh = bf16(final_w * proj_w)   [L, D]
// ---------------------------------------------------------------------------
__global__ __launch_bounds__(256) void cast_uv(const float* __restrict__ Uw,
                                               const float* __restrict__ Fw,
                                               const float* __restrict__ Pw,
                                               unsigned short* __restrict__ uh,
                                               unsigned short* __restrict__ vh) {
    const int total4 = (L_ * D_) / 4;
    int i = blockIdx.x * 256 + threadIdx.x;
    if (i >= total4) return;
    const int base = i * 4;
    const int d = base & (D_ - 1);
    float4 u4 = *(const float4*)(Uw + base);
    float4 f4 = *(const float4*)(Fw + base);
    float4 p4 = *(const float4*)(Pw + d);
    us4 uo, vo;
    uo.x = f2bf(u4.x); uo.y = f2bf(u4.y); uo.z = f2bf(u4.z); uo.w = f2bf(u4.w);
    vo.x = f2bf(f4.x * p4.x); vo.y = f2bf(f4.y * p4.y);
    vo.z = f2bf(f4.z * p4.z); vo.w = f2bf(f4.w * p4.w);
    *(us4*)(uh + base) = uo;
    *(us4*)(vh + base) = vo;
}

// ---------------------------------------------------------------------------
// Kernel 2: xT[b][d][t] = bf16(x[b][t][d]); 32x32 tile.
// float4 global loads, LDS pad 41 (<=2-way, free), us4 stores.
// ---------------------------------------------------------------------------
__global__ __launch_bounds__(256) void transpose_x(const float* __restrict__ x,
                                                   unsigned short* __restrict__ xT) {
    __shared__ float tile[32][41];
    const int b = blockIdx.z;
    const int t0 = blockIdx.x * 32;
    const int d0 = blockIdx.y * 32;
    const int t = threadIdx.x >> 3, dc = (threadIdx.x & 7) * 4;
    float4 v = *(const float4*)(x + (size_t)(b * T_ + t0 + t) * D_ + d0 + dc);
    tile[t][dc] = v.x; tile[t][dc + 1] = v.y;
    tile[t][dc + 2] = v.z; tile[t][dc + 3] = v.w;
    __syncthreads();
    const int d = threadIdx.x >> 3, tc = (threadIdx.x & 7) * 4;
    us4 o;
    o.x = f2bf(tile[tc + 0][d]);
    o.y = f2bf(tile[tc + 1][d]);
    o.z = f2bf(tile[tc + 2][d]);
    o.w = f2bf(tile[tc + 3][d]);
    *(us4*)(xT + (size_t)(b * D_ + d0 + d) * T_ + t0 + tc) = o;
}

// ---------------------------------------------------------------------------
// Kernel 3: split-K symmetric Gram partials. KSPLIT=4 (was 8): halves atomic
// traffic, 2x K-amortization; 320 blocks @ 3/CU. Loop structure proven r3-r6.
// ---------------------------------------------------------------------------
__global__ __launch_bounds__(256) void gramk(const unsigned short* __restrict__ xT,
                                             float* __restrict__ Sf) {
    __shared__ __align__(16) unsigned short lA[3][4096];
    __shared__ __align__(16) unsigned short lB[3][4096];
    const int tid = threadIdx.x;
    const int bid = blockIdx.x;
    const int b = bid & 7;
    const int r2 = bid >> 3;            // 0..39
    const int tile = r2 % 10;
    const int ks = r2 / 10;             // 0..3
    int ti, tj;
    if (tile < 4)      { ti = 0; tj = tile; }
    else if (tile < 7) { ti = 1; tj = tile - 3; }
    else if (tile < 9) { ti = 2; tj = tile - 5; }
    else               { ti = 3; tj = 3; }
    const int i0 = ti * 128, j0 = tj * 128;
    const int kbeg = ks * KCH;
    const int nst = min(KSTEPS_TOT, kbeg + KCH) - kbeg;   // 32 or 29

    const int l = tid & 63;
    const int wv = tid >> 6, wr = wv >> 1, wc = wv & 1;
    const int lr = l & 15, lg = l >> 4;

    const float4v z4 = {0.f, 0.f, 0.f, 0.f};
    float4v acc[4][4];
#pragma unroll
    for (int m = 0; m < 4; m++)
#pragma unroll
        for (int n = 0; n < 4; n++) acc[m][n] = z4;

    const int rl = ((tid >> 3) << 1) | ((tid >> 2) & 1);
    const int sc = ((tid & 3) ^ ((tid >> 3) & 3)) << 3;
    const size_t xb = (size_t)b * D_ * T_;
    const unsigned short* gA0 = xT + xb + (size_t)(i0 + rl) * T_ + kbeg * 32 + sc;
    const unsigned short* gA1 = xT + xb + (size_t)(i0 + 64 + rl) * T_ + kbeg * 32 + sc;
    const unsigned short* gB0 = xT + xb + (size_t)(j0 + rl) * T_ + kbeg * 32 + sc;
    const unsigned short* gB1 = xT + xb + (size_t)(j0 + 64 + rl) * T_ + kbeg * 32 + sc;

#define STAGE_G(bf_, st_)                                                      \
    {                                                                          \
        GLL(gA0 + (st_) * 32, &lA[bf_][tid * 8]);                              \
        GLL(gA1 + (st_) * 32, &lA[bf_][2048 + tid * 8]);                       \
        GLL(gB0 + (st_) * 32, &lB[bf_][tid * 8]);                              \
        GLL(gB1 + (st_) * 32, &lB[bf_][2048 + tid * 8]);                       \
    }

    STAGE_G(0, 0);
    STAGE_G(1, 1);
    int cur = 0;
    for (int s = 0; s < nst; ++s) {
        if (s == nst - 1) asm volatile("s_waitcnt vmcnt(0)" ::: "memory");
        else              asm volatile("s_waitcnt vmcnt(4)" ::: "memory");
        __builtin_amdgcn_s_barrier();
        asm volatile("" ::: "memory");
        if (s + 2 < nst) {
            int nb = cur + 2; if (nb >= 3) nb -= 3;
            STAGE_G(nb, s + 2);
        }
        short8 bfr[4];
#pragma unroll
        for (int n = 0; n < 4; n++)
            bfr[n] = *(const short8*)&lB[cur][swz(wc * 64 + n * 16 + lr, lg)];
        __builtin_amdgcn_s_setprio(1);
#pragma unroll
        for (int m = 0; m < 4; m++) {
            short8 a = *(const short8*)&lA[cur][swz(wr * 64 + m * 16 + lr, lg)];
#pragma unroll
            for (int n = 0; n < 4; n++)
                acc[m][n] = __builtin_amdgcn_mfma_f32_16x16x32_bf16(a, bfr[n], acc[m][n], 0, 0, 0);
        }
        __builtin_amdgcn_s_setprio(0);
        cur = (cur == 2) ? 0 : cur + 1;
    }
#undef STAGE_G

    float* Sb = Sf + (size_t)b * D_ * D_;
#pragma unroll
    for (int m = 0; m < 4; m++)
#pragma unroll
        for (int n = 0; n < 4; n++)
#pragma unroll
            for (int r = 0; r < 4; r++) {
                int row = i0 + wr * 64 + m * 16 + lg * 4 + r;
                int col = j0 + wc * 64 + n * 16 + lr;
                atomicAdd(&Sb[(size_t)row * D_ + col], acc[m][n][r]);
            }
}

// ---------------------------------------------------------------------------
// Kernel 4: Sh = bf16(dense S) from upper-tile Sf. MIRROR-SCATTER version:
// all reads coalesced (float4 rows of the stored upper region); lower tiles
// produced by scalar bf16 scatter-WRITES (fire-and-forget, L2-absorbed).
// Blocks >= 1280 do out[b][l] = final_b[l] init.
// ---------------------------------------------------------------------------
__global__ __launch_bounds__(256) void castS_init(const float* __restrict__ Sf,
                                                  unsigned short* __restrict__ Sh,
                                                  const float* __restrict__ fb,
                                                  float* __restrict__ out) {
    const int blk = blockIdx.x;
    if (blk >= 1280) {
        int k = (blk - 1280) * 256 + threadIdx.x;
        if (k < B_ * L_) {
            int b = k / L_;
            out[k] = fb[k - b * L_];
        }
        return;
    }
    // 160 blocks per batch: 10 upper tiles x 16 blocks (4096 float4-quads/tile)
    const int b = blk / 160;
    const int r = blk % 160;
    const int tile = r >> 4;
    const int sub = r & 15;
    int ti, tj;
    if (tile < 4)      { ti = 0; tj = tile; }
    else if (tile < 7) { ti = 1; tj = tile - 3; }
    else if (tile < 9) { ti = 2; tj = tile - 5; }
    else               { ti = 3; tj = 3; }
    const int q = sub * 256 + threadIdx.x;       // 0..4095
    const int row = ti * 128 + (q >> 5);
    const int col = tj * 128 + (q & 31) * 4;
    const float* Sb = Sf + (size_t)b * D_ * D_;
    unsigned short* Shb = Sh + (size_t)b * D_ * D_;
    float4 v = *(const float4*)(Sb + (size_t)row * D_ + col);
    us4 o;
    o.x = f2bf(v.x); o.y = f2bf(v.y); o.z = f2bf(v.z); o.w = f2bf(v.w);
    *(us4*)(Shb + (size_t)row * D_ + col) = o;
    if (ti != tj) {                              // scatter the mirrored copy
        Shb[(size_t)(col + 0) * D_ + row] = o.x;
        Shb[(size_t)(col + 1) * D_ + row] = o.y;
        Shb[(size_t)(col + 2) * D_ + row] = o.z;
        Shb[(size_t)(col + 3) * D_ + row] = o.w;
    }
}

// ---------------------------------------------------------------------------
// Kernel 5: logits[b,l] += sum_d (U @ S_b)[l,d] * vh[l,d]
// 128x128 tile, 4 waves, 3-ring counted vmcnt(4) (r6 structure, UNCHANGED as
// control). iofs splits the 2240-work grid into two 1120-block dispatches for
// profile visibility (any hidden kernel > ~33us now surfaces in top-5).
// ---------------------------------------------------------------------------
__global__ __launch_bounds__(256) void stage2(const unsigned short* __restrict__ uh,
                                              const unsigned short* __restrict__ vh,
                                              const unsigned short* __restrict__ Sh,
                                              float* __restrict__ out, int iofs) {
    __shared__ __align__(16) unsigned short lA[3][4096];
    __shared__ __align__(16) unsigned short lB[3][4096];
    __shared__ float red[2][128];
    const int tid = threadIdx.x;
    const int w = (blockIdx.x & 7) * 280 + (blockIdx.x >> 3) + iofs;
    const int lt = w >> 5;
    const int rem = w & 31;
    const int dt = rem >> 3;
    const int b = rem & 7;
    const int l0 = lt * 128, d0 = dt * 128;
    const int l = tid & 63;
    const int wv = tid >> 6, wr = wv >> 1, wc = wv & 1;
    const int lr = l & 15, lg = l >> 4;

    const float4v z4 = {0.f, 0.f, 0.f, 0.f};
    float4v acc[4][4];
#pragma unroll
    for (int m = 0; m < 4; m++)
#pragma unroll
        for (int n = 0; n < 4; n++) acc[m][n] = z4;

    const int rl = ((tid >> 3) << 1) | ((tid >> 2) & 1);
    const int sc = ((tid & 3) ^ ((tid >> 3) & 3)) << 3;
    const int rA0 = min(l0 + rl, L_ - 1);
    const int rA1 = min(l0 + 64 + rl, L_ - 1);
    const unsigned short* gA0 = uh + (size_t)rA0 * D_ + sc;
    const unsigned short* gA1 = uh + (size_t)rA1 * D_ + sc;
    const size_t sb = (size_t)b * D_ * D_;
    const unsigned short* gB0 = Sh + sb + (size_t)(d0 + rl) * D_ + sc;
    const unsigned short* gB1 = Sh + sb + (size_t)(d0 + 64 + rl) * D_ + sc;

#define STAGE_S(bf_, st_)                                                      \
    {                                                                          \
        GLL(gA0 + (st_) * 32, &lA[bf_][tid * 8]);                              \
        GLL(gA1 + (st_) * 32, &lA[bf_][2048 + tid * 8]);                       \
        GLL(gB0 + (st_) * 32, &lB[bf_][tid * 8]);                              \
        GLL(gB1 + (st_) * 32, &lB[bf_][2048 + tid * 8]);                       \
    }

    STAGE_S(0, 0);
    STAGE_S(1, 1);
    int cur = 0;
    for (int s = 0; s < 16; ++s) {
        if (s == 15) asm volatile("s_waitcnt vmcnt(0)" ::: "memory");
        else         asm volatile("s_waitcnt vmcnt(4)" ::: "memory");
        __builtin_amdgcn_s_barrier();
        asm volatile("" ::: "memory");
        if (s + 2 < 16) {
            int nb = cur + 2; if (nb >= 3) nb -= 3;
            STAGE_S(nb, s + 2);
        }
        short8 bfr[4];
#pragma unroll
        for (int n = 0; n < 4; n++)
            bfr[n] = *(const short8*)&lB[cur][swz(wc * 64 + n * 16 + lr, lg)];
        __builtin_amdgcn_s_setprio(1);
#pragma unroll
        for (int m = 0; m < 4; m++) {
            short8 a = *(const short8*)&lA[cur][swz(wr * 64 + m * 16 + lr, lg)];
#pragma unroll
            for (int n = 0; n < 4; n++)
                acc[m][n] = __builtin_amdgcn_mfma_f32_16x16x32_bf16(a, bfr[n], acc[m][n], 0, 0, 0);
        }
        __builtin_amdgcn_s_setprio(0);
        cur = (cur == 2) ? 0 : cur + 1;
    }
#undef STAGE_S

    float part[4][4];
#pragma unroll
    for (int m = 0; m < 4; m++)
#pragma unroll
        for (int r = 0; r < 4; r++) part[m][r] = 0.f;
#pragma unroll
    for (int m = 0; m < 4; m++)
#pragma unroll
        for (int n = 0; n < 4; n++) {
            int dcol = d0 + wc * 64 + n * 16 + lr;
#pragma unroll
            for (int r = 0; r < 4; r++) {
                int lrow = l0 + wr * 64 + m * 16 + lg * 4 + r;
                float v = bf2f(vh[(size_t)min(lrow, L_ - 1) * D_ + dcol]);
                part[m][r] += acc[m][n][r] * v;
            }
        }
#pragma unroll
    for (int off = 1; off < 16; off <<= 1)
#pragma unroll
        for (int m = 0; m < 4; m++)
#pragma unroll
            for (int r = 0; r < 4; r++)
                part[m][r] += __shfl_xor(part[m][r], off, 64);
    if (lr == 0) {
#pragma unroll
        for (int m = 0; m < 4; m++)
#pragma unroll
            for (int r = 0; r < 4; r++)
                red[wc][wr * 64 + m * 16 + lg * 4 + r] = part[m][r];
    }
    __syncthreads();
    if (tid < 128) {
        int lrow = l0 + tid;
        if (lrow < L_) atomicAdd(&out[(size_t)b * L_ + lrow], red[0][tid] + red[1][tid]);
    }
}

// ---------------------------------------------------------------------------
extern "C" void kernel_launch(void* const* d_in, const int* in_sizes, int n_in,
                              void* d_out, int out_size, void* d_ws, size_t ws_size,
                              hipStream_t stream) {
    const float* x  = (const float*)d_in[0];
    const float* Uw = (const float*)d_in[1];
    const float* Fw = (const float*)d_in[2];
    const float* fb = (const float*)d_in[3];
    const float* Pw = (const float*)d_in[4];
    float* out = (float*)d_out;

    char* ws = (char*)d_ws;
    unsigned short* xT = (unsigned short*)(ws);                 // 32,768,000 B
    unsigned short* uh = (unsigned short*)(ws + 32768000);      //  9,136,128 B
    unsigned short* vh = (unsigned short*)(ws + 41904128);      //  9,136,128 B
    unsigned short* Sh = (unsigned short*)(ws + 51040256);      //  4,194,304 B
    float*          Sf = (float*)(ws + 55234560);               //  8,388,608 B (total ~63.6 MB)

    hipMemsetAsync(Sf, 0, (size_t)B_ * D_ * D_ * 4, stream);
    hipLaunchKernelGGL(cast_uv, dim3((L_ * D_ / 4 + 255) / 256), dim3(256), 0, stream,
                       Uw, Fw, Pw, uh, vh);
    hipLaunchKernelGGL(transpose_x, dim3(T_ / 32, D_ / 32, B_), dim3(256), 0, stream, x, xT);
    hipLaunchKernelGGL(gramk, dim3(8 * 10 * KSPLIT), dim3(256), 0, stream, xT, Sf);
    hipLaunchKernelGGL(castS_init, dim3(1280 + (B_ * L_ + 255) / 256), dim3(256), 0, stream,
                       Sf, Sh, fb, out);
    hipLaunchKernelGGL(stage2, dim3(1120), dim3(256), 0, stream, uh, vh, Sh, out, 0);
    hipLaunchKernelGGL(stage2, dim3(1120), dim3(256), 0, stream, uh, vh, Sh, out, 140);
}